// Round 1
// baseline (555.898 us; speedup 1.0000x reference)
//
#include <hip/hip_runtime.h>

// CXTRNN: T=512 serial steps, B=4096 chains, HID=50, RANK=6, DIM_S=3, DIM_Y=3, DIM_Z=6.
// share_io=True collapses z-einsums: inp = zsum*(W_in@s + b_in); out = zsum*(W_out@tanh(x)+b_out).
// Layout: 16 lanes per batch element (4096*16 = 65536 threads = 1024 waves = 1/SIMD),
// lane owns 4 h-slots (padded 50->64 with zero weights). Weights in registers.

#define SEQ_T 512
#define NB    4096
#define HPL   4

__device__ __forceinline__ float fexp2(float x) { return __builtin_amdgcn_exp2f(x); }
__device__ __forceinline__ float frcpf(float x) { return __builtin_amdgcn_rcpf(x); }
// tanh(x) = 1 - 2/(exp(2x)+1); exp(2x) = exp2(2*log2e*x). Handles +-inf correctly.
__device__ __forceinline__ float ftanh(float x) {
  return fmaf(-2.f, frcpf(fexp2(2.8853900817779268f * x) + 1.f), 1.f);
}
__device__ __forceinline__ float fsigm(float x) {
  return frcpf(1.f + fexp2(-1.4426950408889634f * x));
}

__global__ __launch_bounds__(256) void cxtrnn_kernel(
    const float* __restrict__ S,  const float* __restrict__ Z,
    const float* __restrict__ U,  const float* __restrict__ V,
    const float* __restrict__ Wi, const float* __restrict__ Bi,
    const float* __restrict__ Wo, const float* __restrict__ Bo,
    const float* __restrict__ NW, const float* __restrict__ NBv,
    float* __restrict__ out)
{
  const int tid   = threadIdx.x;
  const int l     = tid & 15;                      // lane within 16-lane group
  const int b     = (blockIdx.x << 4) + (tid >> 4);
  const int gbase = (tid & 63) & 48;               // group base lane within wave

  // ---- weights into registers (zero-padded for h >= 50) ----
  float vw[HPL][6], uw[HPL][6], wiw[HPL][3], biw[HPL], wow[3][HPL];
#pragma unroll
  for (int i = 0; i < HPL; ++i) {
    const int h = l * HPL + i;
    const bool ok = h < 50;
#pragma unroll
    for (int r = 0; r < 6; ++r) {
      vw[i][r] = ok ? V[h * 6 + r] : 0.f;
      uw[i][r] = ok ? U[h * 6 + r] : 0.f;
    }
#pragma unroll
    for (int c = 0; c < 3; ++c) wiw[i][c] = ok ? Wi[h * 3 + c] : 0.f;
    biw[i] = ok ? Bi[h] : 0.f;
#pragma unroll
    for (int y = 0; y < 3; ++y) wow[y][i] = ok ? Wo[y * 50 + h] : 0.f;
  }
  float nw[6], nb;
  {
    const int r = (l < 6) ? l : 0;   // lane r holds nm_W row r (lanes >=6: dummy)
#pragma unroll
    for (int k = 0; k < 6; ++k) nw[k] = NW[r * 6 + k];
    nb = NBv[r];
  }
  const float bo = (l < 3) ? Bo[l] : 0.f;

  float x[HPL] = {0.f, 0.f, 0.f, 0.f};

  const float* sp = S + (size_t)b * 3;
  const float* zp = Z + (size_t)b * 6;
  float* op = out + (size_t)b * 3 + (l < 3 ? l : 0);

  // preload t = 0 (group lanes read same addresses -> coalesced broadcast)
  float  cs0 = sp[0], cs1 = sp[1], cs2 = sp[2];
  float2 cz0 = *(const float2*)(zp);
  float2 cz1 = *(const float2*)(zp + 2);
  float2 cz2 = *(const float2*)(zp + 4);

#pragma unroll 1
  for (int t = 0; t < SEQ_T; ++t) {
    // prefetch next step's s/z (hides HBM latency across the whole step body)
    float  ns0 = 0.f, ns1 = 0.f, ns2 = 0.f;
    float2 nz0 = {0.f, 0.f}, nz1 = {0.f, 0.f}, nz2 = {0.f, 0.f};
    if (t + 1 < SEQ_T) {
      const float* sn = sp + NB * 3;
      const float* zn = zp + NB * 6;
      ns0 = sn[0]; ns1 = sn[1]; ns2 = sn[2];
      nz0 = *(const float2*)(zn);
      nz1 = *(const float2*)(zn + 2);
      nz2 = *(const float2*)(zn + 4);
    }

    const float zv0 = cz0.x, zv1 = cz0.y, zv2 = cz1.x,
                zv3 = cz1.y, zv4 = cz2.x, zv5 = cz2.y;
    const float zsum = ((zv0 + zv1) + (zv2 + zv3)) + (zv4 + zv5);

    // g[r] = sigmoid(z . nm_W[r] + nm_b[r]) ; lane r computes g[r] (others dummy)
    float ga = nb;
    ga = fmaf(zv0, nw[0], ga); ga = fmaf(zv1, nw[1], ga);
    ga = fmaf(zv2, nw[2], ga); ga = fmaf(zv3, nw[3], ga);
    ga = fmaf(zv4, nw[4], ga); ga = fmaf(zv5, nw[5], ga);
    const float gv = fsigm(ga);

    // partial a[r] = sum_h tanh(x[h]) * V[h][r]
    float pa[6] = {0.f, 0.f, 0.f, 0.f, 0.f, 0.f};
#pragma unroll
    for (int i = 0; i < HPL; ++i) {
      const float th = ftanh(x[i]);
#pragma unroll
      for (int r = 0; r < 6; ++r) pa[r] = fmaf(th, vw[i][r], pa[r]);
    }
    // butterfly all-reduce over the 16-lane group
#pragma unroll
    for (int m = 1; m <= 8; m <<= 1) {
#pragma unroll
      for (int r = 0; r < 6; ++r) pa[r] += __shfl_xor(pa[r], m, 64);
    }
    // ag[r] = a[r] * g[r]  (broadcast g[r] from lane gbase+r)
    float ag[6];
#pragma unroll
    for (int r = 0; r < 6; ++r) ag[r] = pa[r] * __shfl(gv, gbase + r, 64);

    // tmp, inp, state update, tanh, partial out
    float po0 = 0.f, po1 = 0.f, po2 = 0.f;
#pragma unroll
    for (int i = 0; i < HPL; ++i) {
      float tm = 0.f;
#pragma unroll
      for (int r = 0; r < 6; ++r) tm = fmaf(ag[r], uw[i][r], tm);
      float ii = biw[i];
      ii = fmaf(cs0, wiw[i][0], ii);
      ii = fmaf(cs1, wiw[i][1], ii);
      ii = fmaf(cs2, wiw[i][2], ii);
      const float xn = 0.5f * x[i] + 0.5f * fmaf(zsum, ii, tm);
      x[i] = xn;
      const float ty = ftanh(xn);
      po0 = fmaf(ty, wow[0][i], po0);
      po1 = fmaf(ty, wow[1][i], po1);
      po2 = fmaf(ty, wow[2][i], po2);
    }
#pragma unroll
    for (int m = 1; m <= 8; m <<= 1) {
      po0 += __shfl_xor(po0, m, 64);
      po1 += __shfl_xor(po1, m, 64);
      po2 += __shfl_xor(po2, m, 64);
    }
    if (l < 3) {
      const float pv = (l == 0) ? po0 : (l == 1) ? po1 : po2;
      *op = zsum * (pv + bo);
    }

    op += (size_t)NB * 3;
    sp += NB * 3;
    zp += NB * 6;
    cs0 = ns0; cs1 = ns1; cs2 = ns2;
    cz0 = nz0; cz1 = nz1; cz2 = nz2;
  }
}

extern "C" void kernel_launch(void* const* d_in, const int* in_sizes, int n_in,
                              void* d_out, int out_size, void* d_ws, size_t ws_size,
                              hipStream_t stream) {
  const float* S   = (const float*)d_in[0];
  const float* Z   = (const float*)d_in[1];
  const float* U   = (const float*)d_in[2];
  const float* V   = (const float*)d_in[3];
  const float* Wi  = (const float*)d_in[4];
  const float* Bi  = (const float*)d_in[5];
  const float* Wo  = (const float*)d_in[6];
  const float* Bo  = (const float*)d_in[7];
  const float* NW  = (const float*)d_in[8];
  const float* NBv = (const float*)d_in[9];
  float* out = (float*)d_out;

  cxtrnn_kernel<<<dim3(256), dim3(256), 0, stream>>>(
      S, Z, U, V, Wi, Bi, Wo, Bo, NW, NBv, out);
}

// Round 2
// 380.991 us; speedup vs baseline: 1.4591x; 1.4591x over previous
//
#include <hip/hip_runtime.h>

// CXTRNN: T=512 serial steps, B=4096 chains, HID=50, RANK=6.
// share_io collapses z-einsums: inp = zsum*(W_in@s+b_in); out = zsum*(W_out@tanh(x)+b_out).
// 16 lanes/b (65536 thr = 1024 waves = 1/SIMD on 256 CUs), lane owns 4 h-slots (pad 50->64).
// Latency attack: DPP 16-lane reductions (VALU-speed, not LDS), z/s-path prepared one
// step ahead (off the recurrence chain), tanh kept as state (computed once per step).

#define SEQ_T 512
#define NB    4096
#define HPL   4

__device__ __forceinline__ float fexp2(float x) { return __builtin_amdgcn_exp2f(x); }
__device__ __forceinline__ float frcpf(float x) { return __builtin_amdgcn_rcpf(x); }
__device__ __forceinline__ float ftanh(float x) {
  return fmaf(-2.f, frcpf(fexp2(2.8853900817779268f * x) + 1.f), 1.f);
}
__device__ __forceinline__ float fsigm(float x) {
  return frcpf(1.f + fexp2(-1.4426950408889634f * x));
}

template <int CTRL>
__device__ __forceinline__ float dpp_add(float v) {
  int p = __builtin_amdgcn_update_dpp(0, __float_as_int(v), CTRL, 0xF, 0xF, true);
  return v + __int_as_float(p);
}
// 16-lane all-reduce sum at VALU speed: xor1, xor2 (quad sums), then ror4+ror8
// combine the four quad-sums. All lanes end with the full sum.
__device__ __forceinline__ float red16(float v) {
  v = dpp_add<0xB1>(v);     // quad_perm [1,0,3,2] : xor 1
  v = dpp_add<0x4E>(v);     // quad_perm [2,3,0,1] : xor 2
  v = dpp_add<0x124>(v);    // row_ror:4
  v = dpp_add<0x128>(v);    // row_ror:8
  return v;
}

__global__ __launch_bounds__(256) void cxtrnn_kernel(
    const float* __restrict__ S,  const float* __restrict__ Z,
    const float* __restrict__ U,  const float* __restrict__ V,
    const float* __restrict__ Wi, const float* __restrict__ Bi,
    const float* __restrict__ Wo, const float* __restrict__ Bo,
    const float* __restrict__ NW, const float* __restrict__ NBv,
    float* __restrict__ out)
{
  const int tid   = threadIdx.x;
  const int l     = tid & 15;
  const int b     = (blockIdx.x << 4) + (tid >> 4);
  const int gbase = (tid & 63) & 48;

  // ---- weights into registers (zero-padded for h >= 50) ----
  float vw[HPL][6], uw[HPL][6], wiw[HPL][3], biw[HPL], wow[3][HPL];
#pragma unroll
  for (int i = 0; i < HPL; ++i) {
    const int h = l * HPL + i;
    const bool ok = h < 50;
#pragma unroll
    for (int r = 0; r < 6; ++r) {
      vw[i][r] = ok ? V[h * 6 + r] : 0.f;
      uw[i][r] = ok ? U[h * 6 + r] : 0.f;
    }
#pragma unroll
    for (int c = 0; c < 3; ++c) wiw[i][c] = ok ? Wi[h * 3 + c] : 0.f;
    biw[i] = ok ? Bi[h] : 0.f;
#pragma unroll
    for (int y = 0; y < 3; ++y) wow[y][i] = ok ? Wo[y * 50 + h] : 0.f;
  }
  float nw[6], nb;
  {
    const int r = (l < 6) ? l : 0;   // lane r of each group holds nm_W row r
#pragma unroll
    for (int k = 0; k < 6; ++k) nw[k] = NW[r * 6 + k];
    nb = NBv[r];
  }
  const float bo = (l < 3) ? Bo[l] : 0.f;

  float x[HPL]  = {0.f, 0.f, 0.f, 0.f};
  float th[HPL] = {0.f, 0.f, 0.f, 0.f};   // tanh(x), kept as state

  const float* sp = S + (size_t)b * 3;
  const float* zp = Z + (size_t)b * 6;
  float* op = out + (size_t)b * 3 + (l < 3 ? l : 0);

  // prepared step-t quantities (z/s path, off the recurrence chain)
  float zsum_c, gc[6], ii_c[HPL];
  auto prep = [&](float s0, float s1, float s2,
                  float z0, float z1, float z2, float z3, float z4, float z5) {
    zsum_c = ((z0 + z1) + (z2 + z3)) + (z4 + z5);
    float ga = nb;
    ga = fmaf(z0, nw[0], ga); ga = fmaf(z1, nw[1], ga);
    ga = fmaf(z2, nw[2], ga); ga = fmaf(z3, nw[3], ga);
    ga = fmaf(z4, nw[4], ga); ga = fmaf(z5, nw[5], ga);
    const float gv = fsigm(ga);
#pragma unroll
    for (int r = 0; r < 6; ++r) gc[r] = __shfl(gv, gbase + r, 64);
    const float hz = 0.5f * zsum_c;  // fold the ALPHA=0.5 here
#pragma unroll
    for (int i = 0; i < HPL; ++i) {
      float ii = biw[i];
      ii = fmaf(s0, wiw[i][0], ii);
      ii = fmaf(s1, wiw[i][1], ii);
      ii = fmaf(s2, wiw[i][2], ii);
      ii_c[i] = hz * ii;
    }
  };

  // ---- software pipeline fill: load t=0, prep t=0, load t=1 ----
  float lbs0 = sp[0], lbs1 = sp[1], lbs2 = sp[2];
  float lbz0 = zp[0], lbz1 = zp[1], lbz2 = zp[2];
  float lbz3 = zp[3], lbz4 = zp[4], lbz5 = zp[5];
  prep(lbs0, lbs1, lbs2, lbz0, lbz1, lbz2, lbz3, lbz4, lbz5);
  lbs0 = sp[NB * 3 + 0]; lbs1 = sp[NB * 3 + 1]; lbs2 = sp[NB * 3 + 2];
  lbz0 = zp[NB * 6 + 0]; lbz1 = zp[NB * 6 + 1]; lbz2 = zp[NB * 6 + 2];
  lbz3 = zp[NB * 6 + 3]; lbz4 = zp[NB * 6 + 4]; lbz5 = zp[NB * 6 + 5];
  sp += (size_t)2 * NB * 3;
  zp += (size_t)2 * NB * 6;

#pragma unroll 2
  for (int t = 0; t < SEQ_T; ++t) {
    // issue loads for t+2 (consumed by prep one full iteration later)
    float ns0 = 0.f, ns1 = 0.f, ns2 = 0.f;
    float nz0 = 0.f, nz1 = 0.f, nz2 = 0.f, nz3 = 0.f, nz4 = 0.f, nz5 = 0.f;
    if (t + 2 < SEQ_T) {
      ns0 = sp[0]; ns1 = sp[1]; ns2 = sp[2];
      nz0 = zp[0]; nz1 = zp[1]; nz2 = zp[2];
      nz3 = zp[3]; nz4 = zp[4]; nz5 = zp[5];
    }

    // ---- recurrence for step t (critical chain) ----
    float pa[6] = {0.f, 0.f, 0.f, 0.f, 0.f, 0.f};
#pragma unroll
    for (int i = 0; i < HPL; ++i)
#pragma unroll
      for (int r = 0; r < 6; ++r) pa[r] = fmaf(th[i], vw[i][r], pa[r]);
#pragma unroll
    for (int r = 0; r < 6; ++r) pa[r] = red16(pa[r]);
    float ag[6];
#pragma unroll
    for (int r = 0; r < 6; ++r) ag[r] = pa[r] * gc[r];

    float hp[HPL];
#pragma unroll
    for (int i = 0; i < HPL; ++i) hp[i] = fmaf(0.5f, x[i], ii_c[i]);

    float po0 = 0.f, po1 = 0.f, po2 = 0.f;
#pragma unroll
    for (int i = 0; i < HPL; ++i) {
      float tm01 = fmaf(ag[1], uw[i][1], ag[0] * uw[i][0]);
      float tm23 = fmaf(ag[3], uw[i][3], ag[2] * uw[i][2]);
      float tm45 = fmaf(ag[5], uw[i][5], ag[4] * uw[i][4]);
      const float tm = (tm01 + tm23) + tm45;
      const float xn = fmaf(0.5f, tm, hp[i]);
      x[i] = xn;
      const float ty = ftanh(xn);
      th[i] = ty;
      po0 = fmaf(ty, wow[0][i], po0);
      po1 = fmaf(ty, wow[1][i], po1);
      po2 = fmaf(ty, wow[2][i], po2);
    }

    // ---- output for step t (off the recurrence chain) ----
    po0 = red16(po0); po1 = red16(po1); po2 = red16(po2);
    if (l < 3) {
      const float pv = (l == 0) ? po0 : (l == 1) ? po1 : po2;
      *op = zsum_c * (pv + bo);
    }

    // ---- prepare step t+1 from regs loaded one iteration ago ----
    prep(lbs0, lbs1, lbs2, lbz0, lbz1, lbz2, lbz3, lbz4, lbz5);

    // rotate load pipeline
    lbs0 = ns0; lbs1 = ns1; lbs2 = ns2;
    lbz0 = nz0; lbz1 = nz1; lbz2 = nz2;
    lbz3 = nz3; lbz4 = nz4; lbz5 = nz5;
    sp += (size_t)NB * 3;
    zp += (size_t)NB * 6;
    op += (size_t)NB * 3;
  }
}

extern "C" void kernel_launch(void* const* d_in, const int* in_sizes, int n_in,
                              void* d_out, int out_size, void* d_ws, size_t ws_size,
                              hipStream_t stream) {
  const float* S   = (const float*)d_in[0];
  const float* Z   = (const float*)d_in[1];
  const float* U   = (const float*)d_in[2];
  const float* V   = (const float*)d_in[3];
  const float* Wi  = (const float*)d_in[4];
  const float* Bi  = (const float*)d_in[5];
  const float* Wo  = (const float*)d_in[6];
  const float* Bo  = (const float*)d_in[7];
  const float* NW  = (const float*)d_in[8];
  const float* NBv = (const float*)d_in[9];
  float* out = (float*)d_out;

  cxtrnn_kernel<<<dim3(256), dim3(256), 0, stream>>>(
      S, Z, U, V, Wi, Bi, Wo, Bo, NW, NBv, out);
}